// Round 1
// baseline (78.563 us; speedup 1.0000x reference)
//
#include <hip/hip_runtime.h>
#include <hip/hip_bf16.h>
#include <math.h>

// Problem: x, y fp32 [NT=5000, 512, 16] -> scalar
//   per column c (of 8192): sxx=sum x^2, syy=sum y^2, sxy=sum x*y, mx=max|x|
//   cc = -0.001*sxy/((sqrt(sxx)+1e-10)*(sqrt(syy)+1e-10)); out = sum(cc where mx>0)

#define NT_TOTAL 5000
#define NCOL     8192          // 512*16, contiguous inner dims
#define NCOL4    2048          // NCOL/4
#define COLBLK   8             // 8 blocks * 256 threads * 4 cols = 8192 cols

// Phase 1: per-chunk, per-column partial reductions.
// grid = (COLBLK, nchunk); block = 256 threads; each thread handles 4 columns (float4).
__global__ __launch_bounds__(256) void ncc_partial(const float4* __restrict__ x,
                                                   const float4* __restrict__ y,
                                                   float4* __restrict__ ws,
                                                   int clen) {
    const int col4  = blockIdx.x * 256 + threadIdx.x;   // 0..2047
    const int ch    = blockIdx.y;
    int n0 = ch * clen;
    int n1 = n0 + clen;
    if (n1 > NT_TOTAL) n1 = NT_TOTAL;

    const float4* xp = x + (size_t)n0 * NCOL4 + col4;
    const float4* yp = y + (size_t)n0 * NCOL4 + col4;

    float4 sxx = make_float4(0.f, 0.f, 0.f, 0.f);
    float4 syy = make_float4(0.f, 0.f, 0.f, 0.f);
    float4 sxy = make_float4(0.f, 0.f, 0.f, 0.f);
    float4 mx  = make_float4(0.f, 0.f, 0.f, 0.f);

    const int steps = n1 - n0;
    #pragma unroll 4
    for (int i = 0; i < steps; ++i) {
        float4 a = xp[(size_t)i * NCOL4];
        float4 b = yp[(size_t)i * NCOL4];
        sxx.x = fmaf(a.x, a.x, sxx.x);
        sxx.y = fmaf(a.y, a.y, sxx.y);
        sxx.z = fmaf(a.z, a.z, sxx.z);
        sxx.w = fmaf(a.w, a.w, sxx.w);
        syy.x = fmaf(b.x, b.x, syy.x);
        syy.y = fmaf(b.y, b.y, syy.y);
        syy.z = fmaf(b.z, b.z, syy.z);
        syy.w = fmaf(b.w, b.w, syy.w);
        sxy.x = fmaf(a.x, b.x, sxy.x);
        sxy.y = fmaf(a.y, b.y, sxy.y);
        sxy.z = fmaf(a.z, b.z, sxy.z);
        sxy.w = fmaf(a.w, b.w, sxy.w);
        mx.x = fmaxf(mx.x, fabsf(a.x));
        mx.y = fmaxf(mx.y, fabsf(a.y));
        mx.z = fmaxf(mx.z, fabsf(a.z));
        mx.w = fmaxf(mx.w, fabsf(a.w));
    }

    // ws layout (float4 units): [4 kinds][nchunk][NCOL4]
    const int nchunk = gridDim.y;
    float4* SXX = ws;
    float4* SYY = ws + (size_t)nchunk * NCOL4;
    float4* SXY = ws + (size_t)2 * nchunk * NCOL4;
    float4* MX  = ws + (size_t)3 * nchunk * NCOL4;
    const size_t idx = (size_t)ch * NCOL4 + col4;
    SXX[idx] = sxx;
    SYY[idx] = syy;
    SXY[idx] = sxy;
    MX[idx]  = mx;
}

// Phase 2: combine chunks per column, apply nonlinearity + mask, block-reduce.
// grid = 32 blocks * 256 threads = 8192 threads (one per column).
__global__ __launch_bounds__(256) void ncc_combine(const float* __restrict__ ws,
                                                   float* __restrict__ partials,
                                                   int nchunk) {
    const int c = blockIdx.x * 256 + threadIdx.x;   // 0..8191
    const float* SXX = ws;
    const float* SYY = ws + (size_t)nchunk * NCOL;
    const float* SXY = ws + (size_t)2 * nchunk * NCOL;
    const float* MX  = ws + (size_t)3 * nchunk * NCOL;

    float sxx = 0.f, syy = 0.f, sxy = 0.f, mx = 0.f;
    for (int ch = 0; ch < nchunk; ++ch) {
        const size_t idx = (size_t)ch * NCOL + c;
        sxx += SXX[idx];
        syy += SYY[idx];
        sxy += SXY[idx];
        mx = fmaxf(mx, MX[idx]);
    }

    float cc = 0.f;
    if (mx > 0.f) {
        float xn = sqrtf(sxx) + 1e-10f;
        float yn = sqrtf(syy) + 1e-10f;
        cc = -0.001f * sxy / (xn * yn);
    }

    // wave (64-lane) shuffle reduce, then cross-wave via LDS
    for (int off = 32; off > 0; off >>= 1)
        cc += __shfl_down(cc, off);

    __shared__ float red[4];
    const int lane = threadIdx.x & 63;
    const int w    = threadIdx.x >> 6;
    if (lane == 0) red[w] = cc;
    __syncthreads();
    if (threadIdx.x == 0)
        partials[blockIdx.x] = red[0] + red[1] + red[2] + red[3];
}

// Phase 3: sum 32 block partials -> scalar.
__global__ __launch_bounds__(64) void ncc_final(const float* __restrict__ partials,
                                                float* __restrict__ out) {
    float v = (threadIdx.x < 32) ? partials[threadIdx.x] : 0.f;
    for (int off = 32; off > 0; off >>= 1)
        v += __shfl_down(v, off);
    if (threadIdx.x == 0) out[0] = v;
}

extern "C" void kernel_launch(void* const* d_in, const int* in_sizes, int n_in,
                              void* d_out, int out_size, void* d_ws, size_t ws_size,
                              hipStream_t stream) {
    const float* x = (const float*)d_in[0];
    const float* y = (const float*)d_in[1];
    float* out = (float*)d_out;
    float* ws  = (float*)d_ws;

    // Choose chunk count to fit workspace: 4 arrays * nchunk * NCOL floats + 32 partials.
    const size_t per_chunk_bytes = 4ull * NCOL * sizeof(float);  // 128 KiB
    size_t avail = (ws_size > 256) ? (ws_size - 256) : 0;
    int nchunk = (int)(avail / per_chunk_bytes);
    if (nchunk > 50) nchunk = 50;
    if (nchunk < 1)  nchunk = 1;   // degenerate fallback; needs >=128KiB ws
    const int clen = (NT_TOTAL + nchunk - 1) / nchunk;

    float* partials = ws + 4ull * (size_t)nchunk * NCOL;

    dim3 g1(COLBLK, nchunk);
    ncc_partial<<<g1, 256, 0, stream>>>((const float4*)x, (const float4*)y,
                                        (float4*)ws, clen);
    ncc_combine<<<32, 256, 0, stream>>>(ws, partials, nchunk);
    ncc_final<<<1, 64, 0, stream>>>(partials, out);
}